// Round 9
// baseline (485.797 us; speedup 1.0000x reference)
//
#include <hip/hip_runtime.h>
#include <hip/hip_fp16.h>
#include <math.h>

static constexpr float BN_EPS = 1e-5f;
static constexpr float NEG = 0.2f;

typedef float f32x4 __attribute__((ext_vector_type(4)));
typedef _Float16 h16x2 __attribute__((ext_vector_type(2)));
typedef _Float16 h16x8 __attribute__((ext_vector_type(8)));

// ---------------- hist + W-pack + BN-fold fused (chain start) ---------------

__global__ __launch_bounds__(256) void hist_pack(
    const int* __restrict__ ei, int E, int n, int* __restrict__ cnt,
    const float* __restrict__ W0l, const float* __restrict__ W0r,
    const float* __restrict__ W1l, const float* __restrict__ W1r,
    const float* __restrict__ W2l, const float* __restrict__ W2r,
    const float* __restrict__ W3l, const float* __restrict__ W3r,
    __half* __restrict__ pk0, __half* __restrict__ pk1,
    __half* __restrict__ pk2, __half* __restrict__ pk3,
    const float* __restrict__ b0, const float* __restrict__ b1,
    const float* __restrict__ b2,
    const float* __restrict__ g0, const float* __restrict__ g1,
    const float* __restrict__ g2,
    const float* __restrict__ be0, const float* __restrict__ be1,
    const float* __restrict__ be2,
    const float* __restrict__ m0, const float* __restrict__ m1,
    const float* __restrict__ m2,
    const float* __restrict__ v0, const float* __restrict__ v1,
    const float* __restrict__ v2,
    float* __restrict__ bnA, float* __restrict__ bnB) {
    int b = blockIdx.x;
    if (b < 200) {
        if (threadIdx.x >= 64) return;
        const float *Wl, *Wr;
        __half* packed;
        int tile, NTT, M;
        if (b < 192) {
            int layer = b >> 6;
            tile = b & 63;
            NTT = 16; M = 128;
            Wl = (layer == 0) ? W0l : (layer == 1) ? W1l : W2l;
            Wr = (layer == 0) ? W0r : (layer == 1) ? W1r : W2r;
            packed = (layer == 0) ? pk0 : (layer == 1) ? pk1 : pk2;
        } else {
            tile = b - 192;
            NTT = 2; M = 16;
            Wl = W3l; Wr = W3r; packed = pk3;
        }
        int NT = NTT >> 1;
        int gnt = tile % NTT;
        int kt = tile / NTT;
        int l = threadIdx.x;
        const float* W = (gnt < NT) ? Wl : Wr;
        int col = (gnt % NT) * 16 + (l & 15);
        int krow = kt * 32 + ((l >> 4) << 3);
        size_t base = (size_t)tile * 512 + (size_t)l * 8;
#pragma unroll
        for (int j = 0; j < 8; j++)
            packed[base + j] = __float2half(W[(size_t)(krow + j) * M + col]);
    } else if (b == 200) {
        for (int t = threadIdx.x; t < 384; t += 256) {
            int layer = t >> 7;
            int c = t & 127;
            const float* gg = (layer == 0) ? g0 : (layer == 1) ? g1 : g2;
            const float* ee = (layer == 0) ? be0 : (layer == 1) ? be1 : be2;
            const float* mm = (layer == 0) ? m0 : (layer == 1) ? m1 : m2;
            const float* vv = (layer == 0) ? v0 : (layer == 1) ? v1 : v2;
            const float* bb = (layer == 0) ? b0 : (layer == 1) ? b1 : b2;
            float A = gg[c] * rsqrtf(vv[c] + BN_EPS);
            bnA[t] = A;
            bnB[t] = fmaf(bb[c] - mm[c], A, ee[c]);
        }
    } else {
        int e = (b - 201) * 256 + threadIdx.x;
        int ET = E + n;
        if (e >= ET) return;
        int d = (e < E) ? ei[E + e] : (e - E);
        atomicAdd(&cnt[d], 1);
    }
}

// ---------------- CSR scan chain ---------------------------------------------

__device__ __forceinline__ void scan_block_body256(
    const int* __restrict__ cnt, int* __restrict__ rowptr,
    int* __restrict__ bsums, int n, int bid, int* s) {
    int t = threadIdx.x;               // 0..255
    int base = bid * 1024 + t * 4;
    int v0 = 0, v1 = 0, v2 = 0, v3 = 0;
    if (base + 3 < n) {
        v0 = cnt[base];     v1 = cnt[base + 1];
        v2 = cnt[base + 2]; v3 = cnt[base + 3];
    } else {
        if (base < n)     v0 = cnt[base];
        if (base + 1 < n) v1 = cnt[base + 1];
        if (base + 2 < n) v2 = cnt[base + 2];
        if (base + 3 < n) v3 = cnt[base + 3];
    }
    int p1 = v0 + v1, p2 = p1 + v2, p3 = p2 + v3;
    s[t] = p3;
    __syncthreads();
    for (int d = 1; d < 256; d <<= 1) {
        int tt = (t >= d) ? s[t - d] : 0;
        __syncthreads();
        s[t] += tt;
        __syncthreads();
    }
    int ex = s[t] - p3;                // exclusive offset for this thread
    if (base < n)     rowptr[base + 1] = ex + v0;
    if (base + 1 < n) rowptr[base + 2] = ex + p1;
    if (base + 2 < n) rowptr[base + 3] = ex + p2;
    if (base + 3 < n) rowptr[base + 4] = ex + p3;
    if (t == 255) bsums[bid] = s[255];
}

// scan_add2: finalize rowptr, seed fill[v]=rowptr[v] (single-atomic scatter),
// and build the 64-bin degree histogram (LDS-local, one flush per block).
__global__ __launch_bounds__(1024) void scan_add2(
    int* __restrict__ rowptr, const int* __restrict__ bsums, int n, int nb,
    int* __restrict__ fill, const int* __restrict__ cnt, int* __restrict__ dbin) {
    __shared__ int sex;
    __shared__ int hb[64];
    if (threadIdx.x < 64) {
        hb[threadIdx.x] = 0;
        int L = threadIdx.x;
        int v = (L < nb) ? bsums[L] : 0;
#pragma unroll
        for (int d = 1; d < 64; d <<= 1) {
            int t = __shfl_up(v, d);
            if (L >= d) v += t;
        }
        int ex = __shfl_up(v, 1);
        if (L == 0) ex = 0;
        if (L == (int)blockIdx.x) sex = ex;
    }
    __syncthreads();
    int i = blockIdx.x * 1024 + threadIdx.x;
    if (i < n) {
        int fin = rowptr[i + 1] + sex;
        rowptr[i + 1] = fin;
        if (i + 1 < n) fill[i + 1] = fin;
        int deg = cnt[i];
        atomicAdd(&hb[deg < 63 ? deg : 63], 1);
    }
    if (i == 0) { rowptr[0] = 0; fill[0] = 0; }
    __syncthreads();
    if (threadIdx.x < 64 && hb[threadIdx.x])
        atomicAdd(&dbin[threadIdx.x], hb[threadIdx.x]);
}

// scatter: edge blocks write CSR col (single atomic, fill pre-seeded);
// node blocks scatter node IDs into perm in degree-ascending bucket order
// (each block redundantly wave-scans the 64 final bin counts).
__global__ __launch_bounds__(256) void scatter_kernel(
    const int* __restrict__ ei, int E, int n,
    int* __restrict__ fill, int* __restrict__ col, int edgeBlocks,
    const int* __restrict__ cnt, const int* __restrict__ dbin,
    int* __restrict__ dfill, int* __restrict__ perm) {
    int b = blockIdx.x;
    if (b < edgeBlocks) {
        int e = b * 256 + threadIdx.x;
        int ET = E + n;
        if (e >= ET) return;
        int s, d;
        if (e < E) { s = ei[e]; d = ei[E + e]; } else { s = e - E; d = s; }
        int pos = atomicAdd(&fill[d], 1);   // absolute position
        col[pos] = s;
    } else {
        __shared__ int sstart[64];
        if (threadIdx.x < 64) {
            int L = threadIdx.x;
            int v = dbin[L];
#pragma unroll
            for (int d = 1; d < 64; d <<= 1) {
                int t = __shfl_up(v, d);
                if (L >= d) v += t;
            }
            int ex = __shfl_up(v, 1);
            if (L == 0) ex = 0;
            sstart[L] = ex;
        }
        __syncthreads();
        int v = (b - edgeBlocks) * 256 + threadIdx.x;
        if (v < n) {
            int deg = cnt[v];
            int bin = deg < 63 ? deg : 63;
            int pos = sstart[bin] + atomicAdd(&dfill[bin], 1);
            perm[pos] = v;
        }
    }
}

// ---------------- fp16 MFMA dual GEMM: Y1 = X@Wl, Y2 = X@Wr (M=128 each) ----
// SWAPPED-OPERAND epilogue (R6-verified): lane's f32x4 = 4 consecutive output
// cols of one row -> ushort4 stores.

template <bool FIRST>
__device__ __forceinline__ void gemm_body(
    const __half* __restrict__ xh, const float* __restrict__ xf,
    const __half* __restrict__ packed,
    __half* __restrict__ Y1, __half* __restrict__ Y2, int n, int bid,
    _Float16* sA) {
    const int t = threadIdx.x;
    const int row0 = bid * 64;

    for (int c = t; c < 1024; c += 256) {
        int row = c >> 4;
        int off = (c & 15) * 8;
        int gr = row0 + row;
        if (gr >= n) gr = n - 1;
        if (FIRST) {
            float4 v0 = *(const float4*)&xf[(size_t)gr * 128 + off];
            float4 v1 = *(const float4*)&xf[(size_t)gr * 128 + off + 4];
            h16x8 h = {(_Float16)v0.x, (_Float16)v0.y, (_Float16)v0.z, (_Float16)v0.w,
                       (_Float16)v1.x, (_Float16)v1.y, (_Float16)v1.z, (_Float16)v1.w};
            *(h16x8*)&sA[row * 136 + off] = h;
        } else {
            *(h16x8*)&sA[row * 136 + off] = *(const h16x8*)&xh[(size_t)gr * 128 + off];
        }
    }
    __syncthreads();

    const int lane = t & 63;
    const int s = t >> 6;
    const int lr = lane & 15;
    const int kq = (lane >> 4) * 8;

    h16x8 af[4][4];                 // [rt][kt]  (x fragment, B-operand)
#pragma unroll
    for (int rt = 0; rt < 4; rt++)
#pragma unroll
        for (int kt = 0; kt < 4; kt++)
            af[rt][kt] = *(const h16x8*)&sA[(rt * 16 + lr) * 136 + kt * 32 + kq];

    f32x4 acc[4][4];                // [ntl][rt]
#pragma unroll
    for (int a = 0; a < 4; a++)
#pragma unroll
        for (int b = 0; b < 4; b++) acc[a][b] = (f32x4){0.f, 0.f, 0.f, 0.f};

#pragma unroll
    for (int kt = 0; kt < 4; kt++) {
#pragma unroll
        for (int ntl = 0; ntl < 4; ntl++) {
            int nt = s * 4 + ntl;
            h16x8 b = *(const h16x8*)&packed[((size_t)(kt * 16 + nt)) * 512 + lane * 8];
#pragma unroll
            for (int rt = 0; rt < 4; rt++)
                acc[ntl][rt] = __builtin_amdgcn_mfma_f32_16x16x32_f16(b, af[rt][kt], acc[ntl][rt], 0, 0, 0);
        }
    }

    __half* Y = (s < 2) ? Y1 : Y2;
    const int colh = (s & 1) * 64;
    const int rq = (lane >> 4) * 4;
#pragma unroll
    for (int rt = 0; rt < 4; rt++) {
        int row = row0 + rt * 16 + lr;
        if (row >= n) continue;
#pragma unroll
        for (int ntl = 0; ntl < 4; ntl++) {
            int c0 = colh + ntl * 16 + rq;
            ushort4 o = make_ushort4(
                __half_as_ushort(__float2half(acc[ntl][rt][0])),
                __half_as_ushort(__float2half(acc[ntl][rt][1])),
                __half_as_ushort(__float2half(acc[ntl][rt][2])),
                __half_as_ushort(__float2half(acc[ntl][rt][3])));
            *(ushort4*)&Y[(size_t)row * 128 + c0] = o;
        }
    }
}

__global__ __launch_bounds__(256) void gemm_h_big2(
    const __half* __restrict__ xh, const __half* __restrict__ packed,
    __half* __restrict__ Y1, __half* __restrict__ Y2, int n) {
    __shared__ __align__(16) char smem[64 * 136 * 2];
    gemm_body<false>(xh, nullptr, packed, Y1, Y2, n, blockIdx.x, (_Float16*)smem);
}

// fused dispatch: scan blocks + layer-0 GEMM (R5 lesson: no atomics here).
__global__ __launch_bounds__(256) void scanblk_gemm0(
    const int* __restrict__ cnt, int* __restrict__ rowptr,
    int* __restrict__ bsums, int n, int nscan,
    const float* __restrict__ xf, const __half* __restrict__ packed,
    __half* __restrict__ Y1, __half* __restrict__ Y2) {
    __shared__ __align__(16) char smem[64 * 136 * 2];
    int b = blockIdx.x;
    if (b < nscan) {
        scan_block_body256(cnt, rowptr, bsums, n, b, (int*)smem);
    } else {
        gemm_body<true>(nullptr, xf, packed, Y1, Y2, n, b - nscan,
                        (_Float16*)smem);
    }
}

// ---------------- small fp16 GEMM for layer 3 (M=16 each, fp32 out) ----------

__global__ __launch_bounds__(256) void gemm_h_small(
    const __half* __restrict__ xh, const __half* __restrict__ packed,
    float* __restrict__ Y1, float* __restrict__ Y2, int n) {
    int lane = threadIdx.x & 63;
    int wv = blockIdx.x * 4 + (threadIdx.x >> 6);
    int row0 = wv * 16;
    if (row0 >= n) return;
    int r = row0 + (lane & 15);
    int rl = (r >= n) ? (n - 1) : r;
    int kq = (lane >> 4) * 8;

    h16x8 af[4];
#pragma unroll
    for (int kt = 0; kt < 4; kt++)
        af[kt] = *(const h16x8*)&xh[(size_t)rl * 128 + kt * 32 + kq];

    f32x4 acc[2];
    acc[0] = (f32x4){0.f, 0.f, 0.f, 0.f};
    acc[1] = (f32x4){0.f, 0.f, 0.f, 0.f};

#pragma unroll
    for (int kt = 0; kt < 4; kt++) {
#pragma unroll
        for (int nt = 0; nt < 2; nt++) {
            h16x8 b = *(const h16x8*)&packed[((size_t)(kt * 2 + nt)) * 512 + lane * 8];
            acc[nt] = __builtin_amdgcn_mfma_f32_16x16x32_f16(b, af[kt], acc[nt], 0, 0, 0);
        }
    }

    if (r < n) {
        int rq = (lane >> 4) * 4;
#pragma unroll
        for (int nt = 0; nt < 2; nt++) {
            float* Y = (nt == 0) ? Y1 : Y2;
            *(float4*)&Y[(size_t)r * 16 + rq] =
                make_float4(acc[nt][0], acc[nt][1], acc[nt][2], acc[nt][3]);
        }
    }
}

// ---------------- Fused GATv2 aggregate (16-lane group = node) --------------
// R4-proven structure. NEW: nodes processed in degree-sorted order via perm[]
// so the 4 nodes sharing a wave have ~equal degree (divergence max~=mean).

__device__ __forceinline__ float dot8_h(const h16x2* lp, const h16x2* ap) {
#if __has_builtin(__builtin_amdgcn_fdot2)
    float part = __builtin_amdgcn_fdot2(lp[0], ap[0], 0.f, false);
    part = __builtin_amdgcn_fdot2(lp[1], ap[1], part, false);
    part = __builtin_amdgcn_fdot2(lp[2], ap[2], part, false);
    return __builtin_amdgcn_fdot2(lp[3], ap[3], part, false);
#else
    float part = 0.f;
#pragma unroll
    for (int i = 0; i < 4; i++)
        part += (float)lp[i].x * (float)ap[i].x + (float)lp[i].y * (float)ap[i].y;
    return part;
#endif
}

__global__ __launch_bounds__(256) void agg_h(
    const __half* __restrict__ xl, const __half* __restrict__ xr,
    const int* __restrict__ rowptr, const int* __restrict__ col,
    const int* __restrict__ perm,
    const float* __restrict__ att,
    const float* __restrict__ bnA, const float* __restrict__ bnB,
    __half* __restrict__ oh, int n) {
    int g = (blockIdx.x * blockDim.x + threadIdx.x) >> 4;   // group id
    if (g >= n) return;
    int v = perm[g];                                         // degree-sorted
    int L = threadIdx.x & 15;
    int ch = L * 8;

    int beg = rowptr[v];
    int end = rowptr[v + 1];
    int cb = beg;
    int cidx = (cb + L < end) ? col[cb + L] : v;   // 16-edge window, coalesced

    h16x8 rx = *(const h16x8*)&xr[((size_t)v << 7) + ch];
    float4 av0 = *(const float4*)&att[ch];
    float4 av1 = *(const float4*)&att[ch + 4];
    h16x2 a[4] = {{(_Float16)av0.x, (_Float16)av0.y},
                  {(_Float16)av0.z, (_Float16)av0.w},
                  {(_Float16)av1.x, (_Float16)av1.y},
                  {(_Float16)av1.z, (_Float16)av1.w}};
    const h16x8 neg8 = {(_Float16)NEG, (_Float16)NEG, (_Float16)NEG, (_Float16)NEG,
                        (_Float16)NEG, (_Float16)NEG, (_Float16)NEG, (_Float16)NEG};

    float lrun = 0.f;
    float acc[8] = {0.f, 0.f, 0.f, 0.f, 0.f, 0.f, 0.f, 0.f};

    auto proc = [&](h16x8 hv, bool ok) {
        h16x8 s = hv + rx;
        h16x8 l = __builtin_elementwise_max(s, s * neg8);
        const h16x2* lp = (const h16x2*)&l;
        float part = dot8_h(lp, a);
        part += __shfl_xor(part, 1);      // head = lane pair (16 ch)
        float p = ok ? __expf(part) : 0.f;
        lrun += p;
        const _Float16* hp = (const _Float16*)&hv;
#pragma unroll
        for (int k = 0; k < 8; k++) acc[k] = fmaf(p, (float)hp[k], acc[k]);
    };

    while (true) {
        int ce = min(end, cb + 16);
        for (int e = cb; e < ce; e += 4) {    // 4 edges in flight per group
            int off = e - cb;
            h16x8 hv[4];
#pragma unroll
            for (int j = 0; j < 4; j++) {
                int u = __shfl(cidx, off + j, 16);   // masked slots -> v
                hv[j] = *(const h16x8*)&xl[((size_t)u << 7) + ch];
            }
#pragma unroll
            for (int j = 0; j < 4; j++) proc(hv[j], e + j < end);
        }
        cb += 16;
        if (cb >= end) break;
        cidx = (cb + L < end) ? col[cb + L] : v;
    }

    // epilogue: denominators/acc complete in-group; folded-BN affine + ELU
    float inv = 1.0f / lrun;
    float4 A0 = *(const float4*)&bnA[ch];
    float4 A1 = *(const float4*)&bnA[ch + 4];
    float4 B0 = *(const float4*)&bnB[ch];
    float4 B1 = *(const float4*)&bnB[ch + 4];
    float Av[8] = {A0.x, A0.y, A0.z, A0.w, A1.x, A1.y, A1.z, A1.w};
    float Bv[8] = {B0.x, B0.y, B0.z, B0.w, B1.x, B1.y, B1.z, B1.w};
    h16x8 outv;
#pragma unroll
    for (int k = 0; k < 8; k++) {
        float o = fmaf(acc[k], inv * Av[k], Bv[k]);
        o = o > 0.f ? o : expm1f(o);
        outv[k] = (_Float16)o;
    }
    *(h16x8*)&oh[((size_t)v << 7) + ch] = outv;
}

// ---------------- final aggregate (4-lane group = node), fp32, HC=16 --------
// degree-sorted via perm (16 nodes/wave benefits most: E[max16]~2x mean).

__global__ __launch_bounds__(256) void agg_f(
    const float* __restrict__ xl, const float* __restrict__ xr,
    const int* __restrict__ rowptr, const int* __restrict__ col,
    const int* __restrict__ perm,
    const float* __restrict__ att, const float* __restrict__ bias,
    float* __restrict__ out, int n) {
    int g = (blockIdx.x * blockDim.x + threadIdx.x) >> 2;
    if (g >= n) return;
    int v = perm[g];
    int L = threadIdx.x & 3;
    int ch = 4 * L;

    int beg = rowptr[v];
    int end = rowptr[v + 1];
    int cb = beg;
    int cidx = (cb + L < end) ? col[cb + L] : v;   // 4-edge window

    float4 xrv = *(const float4*)&xr[((size_t)v << 4) + ch];
    float4 av = *(const float4*)&att[ch];

    float lrun = 0.f;
    float4 acc = make_float4(0.f, 0.f, 0.f, 0.f);

    while (true) {
        float4 xv[4];
#pragma unroll
        for (int j = 0; j < 4; j++) {
            int u = __shfl(cidx, j, 4);            // masked slots -> v
            xv[j] = *(const float4*)&xl[((size_t)u << 4) + ch];
        }
#pragma unroll
        for (int j = 0; j < 4; j++) {
            bool ok = (cb + j < end);
            float s0 = xv[j].x + xrv.x; s0 = s0 > 0.f ? s0 : NEG * s0;
            float s1 = xv[j].y + xrv.y; s1 = s1 > 0.f ? s1 : NEG * s1;
            float s2 = xv[j].z + xrv.z; s2 = s2 > 0.f ? s2 : NEG * s2;
            float s3 = xv[j].w + xrv.w; s3 = s3 > 0.f ? s3 : NEG * s3;
            float part = fmaf(s0, av.x, fmaf(s1, av.y, fmaf(s2, av.z, s3 * av.w)));
            part += __shfl_xor(part, 1);
            part += __shfl_xor(part, 2);
            float p = ok ? __expf(part) : 0.f;
            lrun += p;
            acc.x = fmaf(p, xv[j].x, acc.x);
            acc.y = fmaf(p, xv[j].y, acc.y);
            acc.z = fmaf(p, xv[j].z, acc.z);
            acc.w = fmaf(p, xv[j].w, acc.w);
        }
        cb += 4;
        if (cb >= end) break;
        cidx = (cb + L < end) ? col[cb + L] : v;
    }

    float inv = 1.0f / lrun;
    float4 b4 = *(const float4*)&bias[ch];
    *(float4*)&out[((size_t)v << 4) + ch] =
        make_float4(fmaf(acc.x, inv, b4.x), fmaf(acc.y, inv, b4.y),
                    fmaf(acc.z, inv, b4.z), fmaf(acc.w, inv, b4.w));
}

// ---------------- launch ----------------

extern "C" void kernel_launch(void* const* d_in, const int* in_sizes, int n_in,
                              void* d_out, int out_size, void* d_ws, size_t ws_size,
                              hipStream_t stream) {
    const float* x = (const float*)d_in[0];
    const int* ei = (const int*)d_in[1];
    const float* Wl[4] = {(const float*)d_in[2], (const float*)d_in[6],
                          (const float*)d_in[10], (const float*)d_in[14]};
    const float* Wr[4] = {(const float*)d_in[3], (const float*)d_in[7],
                          (const float*)d_in[11], (const float*)d_in[15]};
    const float* att[4] = {(const float*)d_in[4], (const float*)d_in[8],
                           (const float*)d_in[12], (const float*)d_in[16]};
    const float* bias[4] = {(const float*)d_in[5], (const float*)d_in[9],
                            (const float*)d_in[13], (const float*)d_in[17]};
    const float* g[3] = {(const float*)d_in[18], (const float*)d_in[22], (const float*)d_in[26]};
    const float* be[3] = {(const float*)d_in[19], (const float*)d_in[23], (const float*)d_in[27]};
    const float* bm[3] = {(const float*)d_in[20], (const float*)d_in[24], (const float*)d_in[28]};
    const float* bv[3] = {(const float*)d_in[21], (const float*)d_in[25], (const float*)d_in[29]};

    const int n = in_sizes[0] / 128;
    const int E = in_sizes[1] / 2;
    const int ET = E + n;

    char* p = (char*)d_ws;
    __half* xh = (__half*)p;           p += (size_t)n * 128 * 2;
    __half* xlh = (__half*)p;          p += (size_t)n * 128 * 2;
    __half* xrh = (__half*)p;          p += (size_t)n * 128 * 2;
    float* xl3 = (float*)p;            p += (size_t)n * 16 * 4;
    float* xr3 = (float*)p;            p += (size_t)n * 16 * 4;
    int* rowptr = (int*)p;            p += (size_t)(n + 4) * 4;
    int* cnt = (int*)p;               p += (size_t)n * 4;
    int* dbin = (int*)p;              p += 256;        // contiguous after cnt
    int* dfill = (int*)p;             p += 256;        // contiguous after dbin
    int* fill = (int*)p;              p += (size_t)n * 4;
    int* perm = (int*)p;              p += (size_t)n * 4;
    int* col = (int*)p;               p += (size_t)ET * 4;
    int* bsums = (int*)p;             p += 256;
    __half* pk[4];
    for (int i = 0; i < 3; i++) { pk[i] = (__half*)p; p += 4 * 16 * 512 * 2; }
    pk[3] = (__half*)p;               p += 4 * 2 * 512 * 2;
    float* bnA = (float*)p;           p += 384 * 4;
    float* bnB = (float*)p;           p += 384 * 4;

    // one memset over cnt + dbin + dfill (contiguous)
    (void)hipMemsetAsync(cnt, 0, (size_t)n * 4 + 512, stream);

    const int tb = 256;
    const int histBlocks = (ET + tb - 1) / tb;
    hist_pack<<<201 + histBlocks, tb, 0, stream>>>(
        ei, E, n, cnt,
        Wl[0], Wr[0], Wl[1], Wr[1], Wl[2], Wr[2], Wl[3], Wr[3],
        pk[0], pk[1], pk[2], pk[3],
        bias[0], bias[1], bias[2],
        g[0], g[1], g[2], be[0], be[1], be[2],
        bm[0], bm[1], bm[2], bv[0], bv[1], bv[2],
        bnA, bnB);

    const int nb = (n + 1023) / 1024;
    const int gb64 = (n + 63) / 64;
    const int gemmBlocksSmall = ((n + 15) / 16 + 3) / 4;
    const int aggBlocksH = (n + 15) / 16;   // 16-lane group per node
    const int aggBlocksF = (n + 63) / 64;   // 4-lane group per node
    const int nodeBlocks = (n + tb - 1) / tb;

    // scan_block co-dispatched with layer-0 GEMM (independent work)
    scanblk_gemm0<<<nb + gb64, 256, 0, stream>>>(
        cnt, rowptr, bsums, n, nb, x, pk[0], xlh, xrh);
    scan_add2<<<nb, 1024, 0, stream>>>(rowptr, bsums, n, nb, fill, cnt, dbin);
    scatter_kernel<<<histBlocks + nodeBlocks, tb, 0, stream>>>(
        ei, E, n, fill, col, histBlocks, cnt, dbin, dfill, perm);

    agg_h<<<aggBlocksH, 256, 0, stream>>>(
        xlh, xrh, rowptr, col, perm, att[0], bnA, bnB, xh, n);
    for (int i = 1; i < 3; i++) {
        gemm_h_big2<<<gb64, 256, 0, stream>>>(xh, pk[i], xlh, xrh, n);
        agg_h<<<aggBlocksH, 256, 0, stream>>>(
            xlh, xrh, rowptr, col, perm, att[i], bnA + 128 * i, bnB + 128 * i, xh, n);
    }
    gemm_h_small<<<gemmBlocksSmall, 256, 0, stream>>>(xh, pk[3], xl3, xr3, n);
    agg_f<<<aggBlocksF, 256, 0, stream>>>(
        xl3, xr3, rowptr, col, perm, att[3], bias[3], (float*)d_out, n);
}

// Round 10
// 334.843 us; speedup vs baseline: 1.4508x; 1.4508x over previous
//
#include <hip/hip_runtime.h>
#include <hip/hip_fp16.h>
#include <math.h>

static constexpr float BN_EPS = 1e-5f;
static constexpr float NEG = 0.2f;

typedef float f32x4 __attribute__((ext_vector_type(4)));
typedef _Float16 h16x2 __attribute__((ext_vector_type(2)));
typedef _Float16 h16x8 __attribute__((ext_vector_type(8)));

// ---------------- hist + W-pack + BN-fold fused (chain start) ---------------

__global__ __launch_bounds__(256) void hist_pack(
    const int* __restrict__ ei, int E, int n, int* __restrict__ cnt,
    const float* __restrict__ W0l, const float* __restrict__ W0r,
    const float* __restrict__ W1l, const float* __restrict__ W1r,
    const float* __restrict__ W2l, const float* __restrict__ W2r,
    const float* __restrict__ W3l, const float* __restrict__ W3r,
    __half* __restrict__ pk0, __half* __restrict__ pk1,
    __half* __restrict__ pk2, __half* __restrict__ pk3,
    const float* __restrict__ b0, const float* __restrict__ b1,
    const float* __restrict__ b2,
    const float* __restrict__ g0, const float* __restrict__ g1,
    const float* __restrict__ g2,
    const float* __restrict__ be0, const float* __restrict__ be1,
    const float* __restrict__ be2,
    const float* __restrict__ m0, const float* __restrict__ m1,
    const float* __restrict__ m2,
    const float* __restrict__ v0, const float* __restrict__ v1,
    const float* __restrict__ v2,
    float* __restrict__ bnA, float* __restrict__ bnB) {
    int b = blockIdx.x;
    if (b < 200) {
        if (threadIdx.x >= 64) return;
        const float *Wl, *Wr;
        __half* packed;
        int tile, NTT, M;
        if (b < 192) {
            int layer = b >> 6;
            tile = b & 63;
            NTT = 16; M = 128;
            Wl = (layer == 0) ? W0l : (layer == 1) ? W1l : W2l;
            Wr = (layer == 0) ? W0r : (layer == 1) ? W1r : W2r;
            packed = (layer == 0) ? pk0 : (layer == 1) ? pk1 : pk2;
        } else {
            tile = b - 192;
            NTT = 2; M = 16;
            Wl = W3l; Wr = W3r; packed = pk3;
        }
        int NT = NTT >> 1;
        int gnt = tile % NTT;
        int kt = tile / NTT;
        int l = threadIdx.x;
        const float* W = (gnt < NT) ? Wl : Wr;
        int col = (gnt % NT) * 16 + (l & 15);
        int krow = kt * 32 + ((l >> 4) << 3);
        size_t base = (size_t)tile * 512 + (size_t)l * 8;
#pragma unroll
        for (int j = 0; j < 8; j++)
            packed[base + j] = __float2half(W[(size_t)(krow + j) * M + col]);
    } else if (b == 200) {
        for (int t = threadIdx.x; t < 384; t += 256) {
            int layer = t >> 7;
            int c = t & 127;
            const float* gg = (layer == 0) ? g0 : (layer == 1) ? g1 : g2;
            const float* ee = (layer == 0) ? be0 : (layer == 1) ? be1 : be2;
            const float* mm = (layer == 0) ? m0 : (layer == 1) ? m1 : m2;
            const float* vv = (layer == 0) ? v0 : (layer == 1) ? v1 : v2;
            const float* bb = (layer == 0) ? b0 : (layer == 1) ? b1 : b2;
            float A = gg[c] * rsqrtf(vv[c] + BN_EPS);
            bnA[t] = A;
            bnB[t] = fmaf(bb[c] - mm[c], A, ee[c]);
        }
    } else {
        int e = (b - 201) * 256 + threadIdx.x;
        int ET = E + n;
        if (e >= ET) return;
        int d = (e < E) ? ei[E + e] : (e - E);
        atomicAdd(&cnt[d], 1);
    }
}

// ---------------- CSR scan chain ---------------------------------------------

__device__ __forceinline__ void scan_block_body256(
    const int* __restrict__ cnt, int* __restrict__ rowptr,
    int* __restrict__ bsums, int n, int bid, int* s) {
    int t = threadIdx.x;               // 0..255
    int base = bid * 1024 + t * 4;
    int v0 = 0, v1 = 0, v2 = 0, v3 = 0;
    if (base + 3 < n) {
        v0 = cnt[base];     v1 = cnt[base + 1];
        v2 = cnt[base + 2]; v3 = cnt[base + 3];
    } else {
        if (base < n)     v0 = cnt[base];
        if (base + 1 < n) v1 = cnt[base + 1];
        if (base + 2 < n) v2 = cnt[base + 2];
        if (base + 3 < n) v3 = cnt[base + 3];
    }
    int p1 = v0 + v1, p2 = p1 + v2, p3 = p2 + v3;
    s[t] = p3;
    __syncthreads();
    for (int d = 1; d < 256; d <<= 1) {
        int tt = (t >= d) ? s[t - d] : 0;
        __syncthreads();
        s[t] += tt;
        __syncthreads();
    }
    int ex = s[t] - p3;                // exclusive offset for this thread
    if (base < n)     rowptr[base + 1] = ex + v0;
    if (base + 1 < n) rowptr[base + 2] = ex + p1;
    if (base + 2 < n) rowptr[base + 3] = ex + p2;
    if (base + 3 < n) rowptr[base + 4] = ex + p3;
    if (t == 255) bsums[bid] = s[255];
}

// scan_add2: finalize rowptr, seed fill[v]=rowptr[v]; ALSO per-block degree
// histogram via LDS atomics whose return value IS the node's rank within
// (block, bin) -> nrank[]; flush per-block histogram to dhist[bid][64].
// [R9 post-mortem: 50k GLOBAL atomics on 64 bins serialized (181us scatter).
//  Counting sort must be block-local + deterministic merge — zero global
//  atomics in the perm path.]
__global__ __launch_bounds__(1024) void scan_add2(
    int* __restrict__ rowptr, const int* __restrict__ bsums, int n, int nb,
    int* __restrict__ fill, const int* __restrict__ cnt,
    int* __restrict__ dhist, int* __restrict__ nrank) {
    __shared__ int sex;
    __shared__ int hb[64];
    if (threadIdx.x < 64) {
        hb[threadIdx.x] = 0;
        int L = threadIdx.x;
        int v = (L < nb) ? bsums[L] : 0;
#pragma unroll
        for (int d = 1; d < 64; d <<= 1) {
            int t = __shfl_up(v, d);
            if (L >= d) v += t;
        }
        int ex = __shfl_up(v, 1);
        if (L == 0) ex = 0;
        if (L == (int)blockIdx.x) sex = ex;
    }
    __syncthreads();
    int i = blockIdx.x * 1024 + threadIdx.x;
    if (i < n) {
        int fin = rowptr[i + 1] + sex;
        rowptr[i + 1] = fin;
        if (i + 1 < n) fill[i + 1] = fin;
        int deg = cnt[i];
        int bin = deg < 63 ? deg : 63;
        nrank[i] = atomicAdd(&hb[bin], 1);   // LDS atomic: rank within (block,bin)
    }
    if (i == 0) { rowptr[0] = 0; fill[0] = 0; }
    __syncthreads();
    if (threadIdx.x < 64)
        dhist[blockIdx.x * 64 + threadIdx.x] = hb[threadIdx.x];
}

// scatter: edge blocks write CSR col (single atomic, fill pre-seeded);
// node blocks place node IDs into perm via deterministic counting sort:
// pos = globalBinStart(bin) + sum_{b'<sb} dhist[b'][bin] + nrank[v].
// Each 256-node block lies in exactly ONE scan-block (256 | 1024).
__global__ __launch_bounds__(256) void scatter_kernel(
    const int* __restrict__ ei, int E, int n,
    int* __restrict__ fill, int* __restrict__ col, int edgeBlocks,
    const int* __restrict__ cnt, const int* __restrict__ dhist, int nbScan,
    const int* __restrict__ nrank, int* __restrict__ perm) {
    int b = blockIdx.x;
    if (b < edgeBlocks) {
        int e = b * 256 + threadIdx.x;
        int ET = E + n;
        if (e >= ET) return;
        int s, d;
        if (e < E) { s = ei[e]; d = ei[E + e]; } else { s = e - E; d = s; }
        int pos = atomicAdd(&fill[d], 1);   // absolute position
        col[pos] = s;
    } else {
        __shared__ int sstart[64];
        int nb0 = b - edgeBlocks;
        int sb = (nb0 * 256) >> 10;          // owning scan-block
        if (threadIdx.x < 64) {
            int t = threadIdx.x;
            int myoff = 0, tot = 0;
            for (int b2 = 0; b2 < nbScan; b2++) {
                int h = dhist[b2 * 64 + t];
                if (b2 < sb) myoff += h;
                tot += h;
            }
            int v = tot;                     // inclusive wave-scan over bins
#pragma unroll
            for (int d = 1; d < 64; d <<= 1) {
                int tt = __shfl_up(v, d);
                if (t >= d) v += tt;
            }
            sstart[t] = (v - tot) + myoff;   // excl bin start + block offset
        }
        __syncthreads();
        int v = nb0 * 256 + threadIdx.x;
        if (v < n) {
            int deg = cnt[v];
            int bin = deg < 63 ? deg : 63;
            perm[sstart[bin] + nrank[v]] = v;
        }
    }
}

// ---------------- fp16 MFMA dual GEMM: Y1 = X@Wl, Y2 = X@Wr (M=128 each) ----
// SWAPPED-OPERAND epilogue (R6-verified): lane's f32x4 = 4 consecutive output
// cols of one row -> ushort4 stores.

template <bool FIRST>
__device__ __forceinline__ void gemm_body(
    const __half* __restrict__ xh, const float* __restrict__ xf,
    const __half* __restrict__ packed,
    __half* __restrict__ Y1, __half* __restrict__ Y2, int n, int bid,
    _Float16* sA) {
    const int t = threadIdx.x;
    const int row0 = bid * 64;

    for (int c = t; c < 1024; c += 256) {
        int row = c >> 4;
        int off = (c & 15) * 8;
        int gr = row0 + row;
        if (gr >= n) gr = n - 1;
        if (FIRST) {
            float4 v0 = *(const float4*)&xf[(size_t)gr * 128 + off];
            float4 v1 = *(const float4*)&xf[(size_t)gr * 128 + off + 4];
            h16x8 h = {(_Float16)v0.x, (_Float16)v0.y, (_Float16)v0.z, (_Float16)v0.w,
                       (_Float16)v1.x, (_Float16)v1.y, (_Float16)v1.z, (_Float16)v1.w};
            *(h16x8*)&sA[row * 136 + off] = h;
        } else {
            *(h16x8*)&sA[row * 136 + off] = *(const h16x8*)&xh[(size_t)gr * 128 + off];
        }
    }
    __syncthreads();

    const int lane = t & 63;
    const int s = t >> 6;
    const int lr = lane & 15;
    const int kq = (lane >> 4) * 8;

    h16x8 af[4][4];                 // [rt][kt]  (x fragment, B-operand)
#pragma unroll
    for (int rt = 0; rt < 4; rt++)
#pragma unroll
        for (int kt = 0; kt < 4; kt++)
            af[rt][kt] = *(const h16x8*)&sA[(rt * 16 + lr) * 136 + kt * 32 + kq];

    f32x4 acc[4][4];                // [ntl][rt]
#pragma unroll
    for (int a = 0; a < 4; a++)
#pragma unroll
        for (int b = 0; b < 4; b++) acc[a][b] = (f32x4){0.f, 0.f, 0.f, 0.f};

#pragma unroll
    for (int kt = 0; kt < 4; kt++) {
#pragma unroll
        for (int ntl = 0; ntl < 4; ntl++) {
            int nt = s * 4 + ntl;
            h16x8 b = *(const h16x8*)&packed[((size_t)(kt * 16 + nt)) * 512 + lane * 8];
#pragma unroll
            for (int rt = 0; rt < 4; rt++)
                acc[ntl][rt] = __builtin_amdgcn_mfma_f32_16x16x32_f16(b, af[rt][kt], acc[ntl][rt], 0, 0, 0);
        }
    }

    __half* Y = (s < 2) ? Y1 : Y2;
    const int colh = (s & 1) * 64;
    const int rq = (lane >> 4) * 4;
#pragma unroll
    for (int rt = 0; rt < 4; rt++) {
        int row = row0 + rt * 16 + lr;
        if (row >= n) continue;
#pragma unroll
        for (int ntl = 0; ntl < 4; ntl++) {
            int c0 = colh + ntl * 16 + rq;
            ushort4 o = make_ushort4(
                __half_as_ushort(__float2half(acc[ntl][rt][0])),
                __half_as_ushort(__float2half(acc[ntl][rt][1])),
                __half_as_ushort(__float2half(acc[ntl][rt][2])),
                __half_as_ushort(__float2half(acc[ntl][rt][3])));
            *(ushort4*)&Y[(size_t)row * 128 + c0] = o;
        }
    }
}

__global__ __launch_bounds__(256) void gemm_h_big2(
    const __half* __restrict__ xh, const __half* __restrict__ packed,
    __half* __restrict__ Y1, __half* __restrict__ Y2, int n) {
    __shared__ __align__(16) char smem[64 * 136 * 2];
    gemm_body<false>(xh, nullptr, packed, Y1, Y2, n, blockIdx.x, (_Float16*)smem);
}

// fused dispatch: scan blocks + layer-0 GEMM (R5 lesson: no atomics here).
__global__ __launch_bounds__(256) void scanblk_gemm0(
    const int* __restrict__ cnt, int* __restrict__ rowptr,
    int* __restrict__ bsums, int n, int nscan,
    const float* __restrict__ xf, const __half* __restrict__ packed,
    __half* __restrict__ Y1, __half* __restrict__ Y2) {
    __shared__ __align__(16) char smem[64 * 136 * 2];
    int b = blockIdx.x;
    if (b < nscan) {
        scan_block_body256(cnt, rowptr, bsums, n, b, (int*)smem);
    } else {
        gemm_body<true>(nullptr, xf, packed, Y1, Y2, n, b - nscan,
                        (_Float16*)smem);
    }
}

// ---------------- small fp16 GEMM for layer 3 (M=16 each, fp32 out) ----------

__global__ __launch_bounds__(256) void gemm_h_small(
    const __half* __restrict__ xh, const __half* __restrict__ packed,
    float* __restrict__ Y1, float* __restrict__ Y2, int n) {
    int lane = threadIdx.x & 63;
    int wv = blockIdx.x * 4 + (threadIdx.x >> 6);
    int row0 = wv * 16;
    if (row0 >= n) return;
    int r = row0 + (lane & 15);
    int rl = (r >= n) ? (n - 1) : r;
    int kq = (lane >> 4) * 8;

    h16x8 af[4];
#pragma unroll
    for (int kt = 0; kt < 4; kt++)
        af[kt] = *(const h16x8*)&xh[(size_t)rl * 128 + kt * 32 + kq];

    f32x4 acc[2];
    acc[0] = (f32x4){0.f, 0.f, 0.f, 0.f};
    acc[1] = (f32x4){0.f, 0.f, 0.f, 0.f};

#pragma unroll
    for (int kt = 0; kt < 4; kt++) {
#pragma unroll
        for (int nt = 0; nt < 2; nt++) {
            h16x8 b = *(const h16x8*)&packed[((size_t)(kt * 2 + nt)) * 512 + lane * 8];
            acc[nt] = __builtin_amdgcn_mfma_f32_16x16x32_f16(b, af[kt], acc[nt], 0, 0, 0);
        }
    }

    if (r < n) {
        int rq = (lane >> 4) * 4;
#pragma unroll
        for (int nt = 0; nt < 2; nt++) {
            float* Y = (nt == 0) ? Y1 : Y2;
            *(float4*)&Y[(size_t)r * 16 + rq] =
                make_float4(acc[nt][0], acc[nt][1], acc[nt][2], acc[nt][3]);
        }
    }
}

// ---------------- Fused GATv2 aggregate (16-lane group = node) --------------
// R4-proven structure; nodes in degree-sorted order via perm[] so the 4 nodes
// sharing a wave have ~equal degree (divergence max ~= mean).

__device__ __forceinline__ float dot8_h(const h16x2* lp, const h16x2* ap) {
#if __has_builtin(__builtin_amdgcn_fdot2)
    float part = __builtin_amdgcn_fdot2(lp[0], ap[0], 0.f, false);
    part = __builtin_amdgcn_fdot2(lp[1], ap[1], part, false);
    part = __builtin_amdgcn_fdot2(lp[2], ap[2], part, false);
    return __builtin_amdgcn_fdot2(lp[3], ap[3], part, false);
#else
    float part = 0.f;
#pragma unroll
    for (int i = 0; i < 4; i++)
        part += (float)lp[i].x * (float)ap[i].x + (float)lp[i].y * (float)ap[i].y;
    return part;
#endif
}

__global__ __launch_bounds__(256) void agg_h(
    const __half* __restrict__ xl, const __half* __restrict__ xr,
    const int* __restrict__ rowptr, const int* __restrict__ col,
    const int* __restrict__ perm,
    const float* __restrict__ att,
    const float* __restrict__ bnA, const float* __restrict__ bnB,
    __half* __restrict__ oh, int n) {
    int g = (blockIdx.x * blockDim.x + threadIdx.x) >> 4;   // group id
    if (g >= n) return;
    int v = perm[g];                                         // degree-sorted
    int L = threadIdx.x & 15;
    int ch = L * 8;

    int beg = rowptr[v];
    int end = rowptr[v + 1];
    int cb = beg;
    int cidx = (cb + L < end) ? col[cb + L] : v;   // 16-edge window, coalesced

    h16x8 rx = *(const h16x8*)&xr[((size_t)v << 7) + ch];
    float4 av0 = *(const float4*)&att[ch];
    float4 av1 = *(const float4*)&att[ch + 4];
    h16x2 a[4] = {{(_Float16)av0.x, (_Float16)av0.y},
                  {(_Float16)av0.z, (_Float16)av0.w},
                  {(_Float16)av1.x, (_Float16)av1.y},
                  {(_Float16)av1.z, (_Float16)av1.w}};
    const h16x8 neg8 = {(_Float16)NEG, (_Float16)NEG, (_Float16)NEG, (_Float16)NEG,
                        (_Float16)NEG, (_Float16)NEG, (_Float16)NEG, (_Float16)NEG};

    float lrun = 0.f;
    float acc[8] = {0.f, 0.f, 0.f, 0.f, 0.f, 0.f, 0.f, 0.f};

    auto proc = [&](h16x8 hv, bool ok) {
        h16x8 s = hv + rx;
        h16x8 l = __builtin_elementwise_max(s, s * neg8);
        const h16x2* lp = (const h16x2*)&l;
        float part = dot8_h(lp, a);
        part += __shfl_xor(part, 1);      // head = lane pair (16 ch)
        float p = ok ? __expf(part) : 0.f;
        lrun += p;
        const _Float16* hp = (const _Float16*)&hv;
#pragma unroll
        for (int k = 0; k < 8; k++) acc[k] = fmaf(p, (float)hp[k], acc[k]);
    };

    while (true) {
        int ce = min(end, cb + 16);
        for (int e = cb; e < ce; e += 4) {    // 4 edges in flight per group
            int off = e - cb;
            h16x8 hv[4];
#pragma unroll
            for (int j = 0; j < 4; j++) {
                int u = __shfl(cidx, off + j, 16);   // masked slots -> v
                hv[j] = *(const h16x8*)&xl[((size_t)u << 7) + ch];
            }
#pragma unroll
            for (int j = 0; j < 4; j++) proc(hv[j], e + j < end);
        }
        cb += 16;
        if (cb >= end) break;
        cidx = (cb + L < end) ? col[cb + L] : v;
    }

    // epilogue: denominators/acc complete in-group; folded-BN affine + ELU
    float inv = 1.0f / lrun;
    float4 A0 = *(const float4*)&bnA[ch];
    float4 A1 = *(const float4*)&bnA[ch + 4];
    float4 B0 = *(const float4*)&bnB[ch];
    float4 B1 = *(const float4*)&bnB[ch + 4];
    float Av[8] = {A0.x, A0.y, A0.z, A0.w, A1.x, A1.y, A1.z, A1.w};
    float Bv[8] = {B0.x, B0.y, B0.z, B0.w, B1.x, B1.y, B1.z, B1.w};
    h16x8 outv;
#pragma unroll
    for (int k = 0; k < 8; k++) {
        float o = fmaf(acc[k], inv * Av[k], Bv[k]);
        o = o > 0.f ? o : expm1f(o);
        outv[k] = (_Float16)o;
    }
    *(h16x8*)&oh[((size_t)v << 7) + ch] = outv;
}

// ---------------- final aggregate (4-lane group = node), fp32, HC=16 --------

__global__ __launch_bounds__(256) void agg_f(
    const float* __restrict__ xl, const float* __restrict__ xr,
    const int* __restrict__ rowptr, const int* __restrict__ col,
    const int* __restrict__ perm,
    const float* __restrict__ att, const float* __restrict__ bias,
    float* __restrict__ out, int n) {
    int g = (blockIdx.x * blockDim.x + threadIdx.x) >> 2;
    if (g >= n) return;
    int v = perm[g];
    int L = threadIdx.x & 3;
    int ch = 4 * L;

    int beg = rowptr[v];
    int end = rowptr[v + 1];
    int cb = beg;
    int cidx = (cb + L < end) ? col[cb + L] : v;   // 4-edge window

    float4 xrv = *(const float4*)&xr[((size_t)v << 4) + ch];
    float4 av = *(const float4*)&att[ch];

    float lrun = 0.f;
    float4 acc = make_float4(0.f, 0.f, 0.f, 0.f);

    while (true) {
        float4 xv[4];
#pragma unroll
        for (int j = 0; j < 4; j++) {
            int u = __shfl(cidx, j, 4);            // masked slots -> v
            xv[j] = *(const float4*)&xl[((size_t)u << 4) + ch];
        }
#pragma unroll
        for (int j = 0; j < 4; j++) {
            bool ok = (cb + j < end);
            float s0 = xv[j].x + xrv.x; s0 = s0 > 0.f ? s0 : NEG * s0;
            float s1 = xv[j].y + xrv.y; s1 = s1 > 0.f ? s1 : NEG * s1;
            float s2 = xv[j].z + xrv.z; s2 = s2 > 0.f ? s2 : NEG * s2;
            float s3 = xv[j].w + xrv.w; s3 = s3 > 0.f ? s3 : NEG * s3;
            float part = fmaf(s0, av.x, fmaf(s1, av.y, fmaf(s2, av.z, s3 * av.w)));
            part += __shfl_xor(part, 1);
            part += __shfl_xor(part, 2);
            float p = ok ? __expf(part) : 0.f;
            lrun += p;
            acc.x = fmaf(p, xv[j].x, acc.x);
            acc.y = fmaf(p, xv[j].y, acc.y);
            acc.z = fmaf(p, xv[j].z, acc.z);
            acc.w = fmaf(p, xv[j].w, acc.w);
        }
        cb += 4;
        if (cb >= end) break;
        cidx = (cb + L < end) ? col[cb + L] : v;
    }

    float inv = 1.0f / lrun;
    float4 b4 = *(const float4*)&bias[ch];
    *(float4*)&out[((size_t)v << 4) + ch] =
        make_float4(fmaf(acc.x, inv, b4.x), fmaf(acc.y, inv, b4.y),
                    fmaf(acc.z, inv, b4.z), fmaf(acc.w, inv, b4.w));
}

// ---------------- launch ----------------

extern "C" void kernel_launch(void* const* d_in, const int* in_sizes, int n_in,
                              void* d_out, int out_size, void* d_ws, size_t ws_size,
                              hipStream_t stream) {
    const float* x = (const float*)d_in[0];
    const int* ei = (const int*)d_in[1];
    const float* Wl[4] = {(const float*)d_in[2], (const float*)d_in[6],
                          (const float*)d_in[10], (const float*)d_in[14]};
    const float* Wr[4] = {(const float*)d_in[3], (const float*)d_in[7],
                          (const float*)d_in[11], (const float*)d_in[15]};
    const float* att[4] = {(const float*)d_in[4], (const float*)d_in[8],
                           (const float*)d_in[12], (const float*)d_in[16]};
    const float* bias[4] = {(const float*)d_in[5], (const float*)d_in[9],
                            (const float*)d_in[13], (const float*)d_in[17]};
    const float* g[3] = {(const float*)d_in[18], (const float*)d_in[22], (const float*)d_in[26]};
    const float* be[3] = {(const float*)d_in[19], (const float*)d_in[23], (const float*)d_in[27]};
    const float* bm[3] = {(const float*)d_in[20], (const float*)d_in[24], (const float*)d_in[28]};
    const float* bv[3] = {(const float*)d_in[21], (const float*)d_in[25], (const float*)d_in[29]};

    const int n = in_sizes[0] / 128;
    const int E = in_sizes[1] / 2;
    const int ET = E + n;

    char* p = (char*)d_ws;
    __half* xh = (__half*)p;           p += (size_t)n * 128 * 2;
    __half* xlh = (__half*)p;          p += (size_t)n * 128 * 2;
    __half* xrh = (__half*)p;          p += (size_t)n * 128 * 2;
    float* xl3 = (float*)p;            p += (size_t)n * 16 * 4;
    float* xr3 = (float*)p;            p += (size_t)n * 16 * 4;
    int* rowptr = (int*)p;            p += (size_t)(n + 4) * 4;
    int* cnt = (int*)p;               p += (size_t)n * 4;
    int* fill = (int*)p;              p += (size_t)n * 4;
    int* nrank = (int*)p;             p += (size_t)n * 4;
    int* perm = (int*)p;              p += (size_t)n * 4;
    int* dhist = (int*)p;             p += 64 * 64 * 4;   // nbScan<=64 blocks x 64 bins
    int* col = (int*)p;               p += (size_t)ET * 4;
    int* bsums = (int*)p;             p += 256;
    __half* pk[4];
    for (int i = 0; i < 3; i++) { pk[i] = (__half*)p; p += 4 * 16 * 512 * 2; }
    pk[3] = (__half*)p;               p += 4 * 2 * 512 * 2;
    float* bnA = (float*)p;           p += 384 * 4;
    float* bnB = (float*)p;           p += 384 * 4;

    // memset only cnt (fill/nrank/perm/dhist fully written downstream)
    (void)hipMemsetAsync(cnt, 0, (size_t)n * 4, stream);

    const int tb = 256;
    const int histBlocks = (ET + tb - 1) / tb;
    hist_pack<<<201 + histBlocks, tb, 0, stream>>>(
        ei, E, n, cnt,
        Wl[0], Wr[0], Wl[1], Wr[1], Wl[2], Wr[2], Wl[3], Wr[3],
        pk[0], pk[1], pk[2], pk[3],
        bias[0], bias[1], bias[2],
        g[0], g[1], g[2], be[0], be[1], be[2],
        bm[0], bm[1], bm[2], bv[0], bv[1], bv[2],
        bnA, bnB);

    const int nb = (n + 1023) / 1024;
    const int gb64 = (n + 63) / 64;
    const int gemmBlocksSmall = ((n + 15) / 16 + 3) / 4;
    const int aggBlocksH = (n + 15) / 16;   // 16-lane group per node
    const int aggBlocksF = (n + 63) / 64;   // 4-lane group per node
    const int nodeBlocks = (n + tb - 1) / tb;

    // scan_block co-dispatched with layer-0 GEMM (independent work)
    scanblk_gemm0<<<nb + gb64, 256, 0, stream>>>(
        cnt, rowptr, bsums, n, nb, x, pk[0], xlh, xrh);
    scan_add2<<<nb, 1024, 0, stream>>>(rowptr, bsums, n, nb, fill, cnt, dhist, nrank);
    scatter_kernel<<<histBlocks + nodeBlocks, tb, 0, stream>>>(
        ei, E, n, fill, col, histBlocks, cnt, dhist, nb, nrank, perm);

    agg_h<<<aggBlocksH, 256, 0, stream>>>(
        xlh, xrh, rowptr, col, perm, att[0], bnA, bnB, xh, n);
    for (int i = 1; i < 3; i++) {
        gemm_h_big2<<<gb64, 256, 0, stream>>>(xh, pk[i], xlh, xrh, n);
        agg_h<<<aggBlocksH, 256, 0, stream>>>(
            xlh, xrh, rowptr, col, perm, att[i], bnA + 128 * i, bnB + 128 * i, xh, n);
    }
    gemm_h_small<<<gemmBlocksSmall, 256, 0, stream>>>(xh, pk[3], xl3, xr3, n);
    agg_f<<<aggBlocksF, 256, 0, stream>>>(
        xl3, xr3, rowptr, col, perm, att[3], bias[3], (float*)d_out, n);
}

// Round 11
// 330.943 us; speedup vs baseline: 1.4679x; 1.0118x over previous
//
#include <hip/hip_runtime.h>
#include <hip/hip_fp16.h>
#include <math.h>

static constexpr float BN_EPS = 1e-5f;
static constexpr float NEG = 0.2f;

typedef float f32x4 __attribute__((ext_vector_type(4)));
typedef _Float16 h16x2 __attribute__((ext_vector_type(2)));
typedef _Float16 h16x8 __attribute__((ext_vector_type(8)));

// ---------------- hist + W-pack + BN-fold fused (chain start) ---------------

__global__ __launch_bounds__(256) void hist_pack(
    const int* __restrict__ ei, int E, int n, int* __restrict__ cnt,
    const float* __restrict__ W0l, const float* __restrict__ W0r,
    const float* __restrict__ W1l, const float* __restrict__ W1r,
    const float* __restrict__ W2l, const float* __restrict__ W2r,
    const float* __restrict__ W3l, const float* __restrict__ W3r,
    __half* __restrict__ pk0, __half* __restrict__ pk1,
    __half* __restrict__ pk2, __half* __restrict__ pk3,
    const float* __restrict__ b0, const float* __restrict__ b1,
    const float* __restrict__ b2,
    const float* __restrict__ g0, const float* __restrict__ g1,
    const float* __restrict__ g2,
    const float* __restrict__ be0, const float* __restrict__ be1,
    const float* __restrict__ be2,
    const float* __restrict__ m0, const float* __restrict__ m1,
    const float* __restrict__ m2,
    const float* __restrict__ v0, const float* __restrict__ v1,
    const float* __restrict__ v2,
    float* __restrict__ bnA, float* __restrict__ bnB) {
    int b = blockIdx.x;
    if (b < 200) {
        if (threadIdx.x >= 64) return;
        const float *Wl, *Wr;
        __half* packed;
        int tile, NTT, M;
        if (b < 192) {
            int layer = b >> 6;
            tile = b & 63;
            NTT = 16; M = 128;
            Wl = (layer == 0) ? W0l : (layer == 1) ? W1l : W2l;
            Wr = (layer == 0) ? W0r : (layer == 1) ? W1r : W2r;
            packed = (layer == 0) ? pk0 : (layer == 1) ? pk1 : pk2;
        } else {
            tile = b - 192;
            NTT = 2; M = 16;
            Wl = W3l; Wr = W3r; packed = pk3;
        }
        int NT = NTT >> 1;
        int gnt = tile % NTT;
        int kt = tile / NTT;
        int l = threadIdx.x;
        const float* W = (gnt < NT) ? Wl : Wr;
        int col = (gnt % NT) * 16 + (l & 15);
        int krow = kt * 32 + ((l >> 4) << 3);
        size_t base = (size_t)tile * 512 + (size_t)l * 8;
#pragma unroll
        for (int j = 0; j < 8; j++)
            packed[base + j] = __float2half(W[(size_t)(krow + j) * M + col]);
    } else if (b == 200) {
        for (int t = threadIdx.x; t < 384; t += 256) {
            int layer = t >> 7;
            int c = t & 127;
            const float* gg = (layer == 0) ? g0 : (layer == 1) ? g1 : g2;
            const float* ee = (layer == 0) ? be0 : (layer == 1) ? be1 : be2;
            const float* mm = (layer == 0) ? m0 : (layer == 1) ? m1 : m2;
            const float* vv = (layer == 0) ? v0 : (layer == 1) ? v1 : v2;
            const float* bb = (layer == 0) ? b0 : (layer == 1) ? b1 : b2;
            float A = gg[c] * rsqrtf(vv[c] + BN_EPS);
            bnA[t] = A;
            bnB[t] = fmaf(bb[c] - mm[c], A, ee[c]);
        }
    } else {
        int e = (b - 201) * 256 + threadIdx.x;
        int ET = E + n;
        if (e >= ET) return;
        int d = (e < E) ? ei[E + e] : (e - E);
        atomicAdd(&cnt[d], 1);
    }
}

// ---------------- CSR scan chain ---------------------------------------------
// scan blocks write the RAW per-block inclusive scan (rowraw) + block sums;
// the scatfin dispatch finalizes rowfin and scatters col in one pass.

__device__ __forceinline__ void scan_block_body256(
    const int* __restrict__ cnt, int* __restrict__ rowptr,
    int* __restrict__ bsums, int n, int bid, int* s) {
    int t = threadIdx.x;               // 0..255
    int base = bid * 1024 + t * 4;
    int v0 = 0, v1 = 0, v2 = 0, v3 = 0;
    if (base + 3 < n) {
        v0 = cnt[base];     v1 = cnt[base + 1];
        v2 = cnt[base + 2]; v3 = cnt[base + 3];
    } else {
        if (base < n)     v0 = cnt[base];
        if (base + 1 < n) v1 = cnt[base + 1];
        if (base + 2 < n) v2 = cnt[base + 2];
        if (base + 3 < n) v3 = cnt[base + 3];
    }
    int p1 = v0 + v1, p2 = p1 + v2, p3 = p2 + v3;
    s[t] = p3;
    __syncthreads();
    for (int d = 1; d < 256; d <<= 1) {
        int tt = (t >= d) ? s[t - d] : 0;
        __syncthreads();
        s[t] += tt;
        __syncthreads();
    }
    int ex = s[t] - p3;                // exclusive offset for this thread
    if (base < n)     rowptr[base + 1] = ex + v0;
    if (base + 1 < n) rowptr[base + 2] = ex + p1;
    if (base + 2 < n) rowptr[base + 3] = ex + p2;
    if (base + 3 < n) rowptr[base + 4] = ex + p3;
    if (t == 255) bsums[bid] = s[255];
}

// scatfin: one dispatch = rowptr-finalize blocks + edge-scatter blocks.
// Every block redundantly wave-scans the <=64 bsums (cheap) into spre.
// finalize: rowfin[i+1] = rowraw[i+1] + spre[i>>10]; scatter: base =
// (d==0)?0:(rowraw[d]+spre[(d-1)>>10]); col[base + atomicAdd(fill[d])] = s.
// [R5 lesson: this fusion is safe WITHOUT a co-dispatched GEMM — the R5
//  regression was the GEMM's LDS footprint + L2 write thrash, not this math.]
__global__ __launch_bounds__(256) void scatfin(
    const int* __restrict__ ei, int E, int n,
    const int* __restrict__ rowraw, const int* __restrict__ bsums, int nb,
    int* __restrict__ fill, int* __restrict__ col, int* __restrict__ rowfin,
    int nbF) {
    __shared__ int spre[64];
    if (threadIdx.x < 64) {
        int L = threadIdx.x;
        int bv = (L < nb) ? bsums[L] : 0;
#pragma unroll
        for (int d = 1; d < 64; d <<= 1) {
            int t = __shfl_up(bv, d);
            if (L >= d) bv += t;
        }
        int ex = __shfl_up(bv, 1);
        if (L == 0) ex = 0;
        spre[L] = ex;
    }
    __syncthreads();
    int b = blockIdx.x;
    if (b < nbF) {
        int i0 = b * 1024 + threadIdx.x * 4;
#pragma unroll
        for (int j = 0; j < 4; j++) {
            int i = i0 + j;
            if (i < n) rowfin[i + 1] = rowraw[i + 1] + spre[i >> 10];
        }
        if (b == 0 && threadIdx.x == 0) rowfin[0] = 0;
    } else {
        int e = (b - nbF) * 256 + threadIdx.x;
        int ET = E + n;
        if (e >= ET) return;
        int s, d;
        if (e < E) { s = ei[e]; d = ei[E + e]; } else { s = e - E; d = s; }
        int pos = atomicAdd(&fill[d], 1);
        int base = (d == 0) ? 0 : (rowraw[d] + spre[(d - 1) >> 10]);
        col[base + pos] = s;
    }
}

// ---------------- fp16 MFMA dual GEMM: Y1 = X@Wl, Y2 = X@Wr (M=128 each) ----
// SWAPPED-OPERAND epilogue (R6-verified): lane's f32x4 = 4 consecutive output
// cols of one row -> ushort4 stores.

template <bool FIRST>
__device__ __forceinline__ void gemm_body(
    const __half* __restrict__ xh, const float* __restrict__ xf,
    const __half* __restrict__ packed,
    __half* __restrict__ Y1, __half* __restrict__ Y2, int n, int bid,
    _Float16* sA) {
    const int t = threadIdx.x;
    const int row0 = bid * 64;

    for (int c = t; c < 1024; c += 256) {
        int row = c >> 4;
        int off = (c & 15) * 8;
        int gr = row0 + row;
        if (gr >= n) gr = n - 1;
        if (FIRST) {
            float4 v0 = *(const float4*)&xf[(size_t)gr * 128 + off];
            float4 v1 = *(const float4*)&xf[(size_t)gr * 128 + off + 4];
            h16x8 h = {(_Float16)v0.x, (_Float16)v0.y, (_Float16)v0.z, (_Float16)v0.w,
                       (_Float16)v1.x, (_Float16)v1.y, (_Float16)v1.z, (_Float16)v1.w};
            *(h16x8*)&sA[row * 136 + off] = h;
        } else {
            *(h16x8*)&sA[row * 136 + off] = *(const h16x8*)&xh[(size_t)gr * 128 + off];
        }
    }
    __syncthreads();

    const int lane = t & 63;
    const int s = t >> 6;
    const int lr = lane & 15;
    const int kq = (lane >> 4) * 8;

    h16x8 af[4][4];                 // [rt][kt]  (x fragment, B-operand)
#pragma unroll
    for (int rt = 0; rt < 4; rt++)
#pragma unroll
        for (int kt = 0; kt < 4; kt++)
            af[rt][kt] = *(const h16x8*)&sA[(rt * 16 + lr) * 136 + kt * 32 + kq];

    f32x4 acc[4][4];                // [ntl][rt]
#pragma unroll
    for (int a = 0; a < 4; a++)
#pragma unroll
        for (int b = 0; b < 4; b++) acc[a][b] = (f32x4){0.f, 0.f, 0.f, 0.f};

#pragma unroll
    for (int kt = 0; kt < 4; kt++) {
#pragma unroll
        for (int ntl = 0; ntl < 4; ntl++) {
            int nt = s * 4 + ntl;
            h16x8 b = *(const h16x8*)&packed[((size_t)(kt * 16 + nt)) * 512 + lane * 8];
#pragma unroll
            for (int rt = 0; rt < 4; rt++)
                acc[ntl][rt] = __builtin_amdgcn_mfma_f32_16x16x32_f16(b, af[rt][kt], acc[ntl][rt], 0, 0, 0);
        }
    }

    __half* Y = (s < 2) ? Y1 : Y2;
    const int colh = (s & 1) * 64;
    const int rq = (lane >> 4) * 4;
#pragma unroll
    for (int rt = 0; rt < 4; rt++) {
        int row = row0 + rt * 16 + lr;
        if (row >= n) continue;
#pragma unroll
        for (int ntl = 0; ntl < 4; ntl++) {
            int c0 = colh + ntl * 16 + rq;
            ushort4 o = make_ushort4(
                __half_as_ushort(__float2half(acc[ntl][rt][0])),
                __half_as_ushort(__float2half(acc[ntl][rt][1])),
                __half_as_ushort(__float2half(acc[ntl][rt][2])),
                __half_as_ushort(__float2half(acc[ntl][rt][3])));
            *(ushort4*)&Y[(size_t)row * 128 + c0] = o;
        }
    }
}

__global__ __launch_bounds__(256) void gemm_h_big2(
    const __half* __restrict__ xh, const __half* __restrict__ packed,
    __half* __restrict__ Y1, __half* __restrict__ Y2, int n) {
    __shared__ __align__(16) char smem[64 * 136 * 2];
    gemm_body<false>(xh, nullptr, packed, Y1, Y2, n, blockIdx.x, (_Float16*)smem);
}

// fused dispatch: scan blocks + layer-0 GEMM (R5 lesson: no atomics here).
__global__ __launch_bounds__(256) void scanblk_gemm0(
    const int* __restrict__ cnt, int* __restrict__ rowraw,
    int* __restrict__ bsums, int n, int nscan,
    const float* __restrict__ xf, const __half* __restrict__ packed,
    __half* __restrict__ Y1, __half* __restrict__ Y2) {
    __shared__ __align__(16) char smem[64 * 136 * 2];
    int b = blockIdx.x;
    if (b < nscan) {
        scan_block_body256(cnt, rowraw, bsums, n, b, (int*)smem);
    } else {
        gemm_body<true>(nullptr, xf, packed, Y1, Y2, n, b - nscan,
                        (_Float16*)smem);
    }
}

// ---------------- small fp16 GEMM for layer 3 (M=16 each, fp32 out) ----------

__global__ __launch_bounds__(256) void gemm_h_small(
    const __half* __restrict__ xh, const __half* __restrict__ packed,
    float* __restrict__ Y1, float* __restrict__ Y2, int n) {
    int lane = threadIdx.x & 63;
    int wv = blockIdx.x * 4 + (threadIdx.x >> 6);
    int row0 = wv * 16;
    if (row0 >= n) return;
    int r = row0 + (lane & 15);
    int rl = (r >= n) ? (n - 1) : r;
    int kq = (lane >> 4) * 8;

    h16x8 af[4];
#pragma unroll
    for (int kt = 0; kt < 4; kt++)
        af[kt] = *(const h16x8*)&xh[(size_t)rl * 128 + kt * 32 + kq];

    f32x4 acc[2];
    acc[0] = (f32x4){0.f, 0.f, 0.f, 0.f};
    acc[1] = (f32x4){0.f, 0.f, 0.f, 0.f};

#pragma unroll
    for (int kt = 0; kt < 4; kt++) {
#pragma unroll
        for (int nt = 0; nt < 2; nt++) {
            h16x8 b = *(const h16x8*)&packed[((size_t)(kt * 2 + nt)) * 512 + lane * 8];
            acc[nt] = __builtin_amdgcn_mfma_f32_16x16x32_f16(b, af[kt], acc[nt], 0, 0, 0);
        }
    }

    if (r < n) {
        int rq = (lane >> 4) * 4;
#pragma unroll
        for (int nt = 0; nt < 2; nt++) {
            float* Y = (nt == 0) ? Y1 : Y2;
            *(float4*)&Y[(size_t)r * 16 + rq] =
                make_float4(acc[nt][0], acc[nt][1], acc[nt][2], acc[nt][3]);
        }
    }
}

// ---------------- Fused GATv2 aggregate (16-lane group = node) --------------
// R4/R8-proven structure (degree-sort reverted: R10 showed null-to-negative).
// NEW: 8 gathers issued per batch (was 4) -> deeper memory pipeline on the
// random-gather L2-miss path, which the R10 evidence says is the agg floor.

__device__ __forceinline__ float dot8_h(const h16x2* lp, const h16x2* ap) {
#if __has_builtin(__builtin_amdgcn_fdot2)
    float part = __builtin_amdgcn_fdot2(lp[0], ap[0], 0.f, false);
    part = __builtin_amdgcn_fdot2(lp[1], ap[1], part, false);
    part = __builtin_amdgcn_fdot2(lp[2], ap[2], part, false);
    return __builtin_amdgcn_fdot2(lp[3], ap[3], part, false);
#else
    float part = 0.f;
#pragma unroll
    for (int i = 0; i < 4; i++)
        part += (float)lp[i].x * (float)ap[i].x + (float)lp[i].y * (float)ap[i].y;
    return part;
#endif
}

__global__ __launch_bounds__(256) void agg_h(
    const __half* __restrict__ xl, const __half* __restrict__ xr,
    const int* __restrict__ rowptr, const int* __restrict__ col,
    const float* __restrict__ att,
    const float* __restrict__ bnA, const float* __restrict__ bnB,
    __half* __restrict__ oh, int n) {
    int v = (blockIdx.x * blockDim.x + threadIdx.x) >> 4;   // node per 16-lane group
    if (v >= n) return;
    int L = threadIdx.x & 15;
    int ch = L * 8;

    int beg = rowptr[v];
    int end = rowptr[v + 1];
    int cb = beg;
    int cidx = (cb + L < end) ? col[cb + L] : v;   // 16-edge window, coalesced

    h16x8 rx = *(const h16x8*)&xr[((size_t)v << 7) + ch];
    float4 av0 = *(const float4*)&att[ch];
    float4 av1 = *(const float4*)&att[ch + 4];
    h16x2 a[4] = {{(_Float16)av0.x, (_Float16)av0.y},
                  {(_Float16)av0.z, (_Float16)av0.w},
                  {(_Float16)av1.x, (_Float16)av1.y},
                  {(_Float16)av1.z, (_Float16)av1.w}};
    const h16x8 neg8 = {(_Float16)NEG, (_Float16)NEG, (_Float16)NEG, (_Float16)NEG,
                        (_Float16)NEG, (_Float16)NEG, (_Float16)NEG, (_Float16)NEG};

    float lrun = 0.f;
    float acc[8] = {0.f, 0.f, 0.f, 0.f, 0.f, 0.f, 0.f, 0.f};

    auto proc = [&](h16x8 hv, bool ok) {
        h16x8 s = hv + rx;
        h16x8 l = __builtin_elementwise_max(s, s * neg8);
        const h16x2* lp = (const h16x2*)&l;
        float part = dot8_h(lp, a);
        part += __shfl_xor(part, 1);      // head = lane pair (16 ch)
        float p = ok ? __expf(part) : 0.f;
        lrun += p;
        const _Float16* hp = (const _Float16*)&hv;
#pragma unroll
        for (int k = 0; k < 8; k++) acc[k] = fmaf(p, (float)hp[k], acc[k]);
    };

    while (true) {
        int ce = min(end, cb + 16);
        for (int e = cb; e < ce; e += 8) {    // 8 edges in flight per group
            int off = e - cb;
            h16x8 hv[8];
#pragma unroll
            for (int j = 0; j < 8; j++) {
                int u = __shfl(cidx, off + j, 16);   // masked slots -> v
                hv[j] = *(const h16x8*)&xl[((size_t)u << 7) + ch];
            }
#pragma unroll
            for (int j = 0; j < 8; j++) proc(hv[j], e + j < end);
        }
        cb += 16;
        if (cb >= end) break;
        cidx = (cb + L < end) ? col[cb + L] : v;
    }

    // epilogue: denominators/acc complete in-group; folded-BN affine + ELU
    float inv = 1.0f / lrun;
    float4 A0 = *(const float4*)&bnA[ch];
    float4 A1 = *(const float4*)&bnA[ch + 4];
    float4 B0 = *(const float4*)&bnB[ch];
    float4 B1 = *(const float4*)&bnB[ch + 4];
    float Av[8] = {A0.x, A0.y, A0.z, A0.w, A1.x, A1.y, A1.z, A1.w};
    float Bv[8] = {B0.x, B0.y, B0.z, B0.w, B1.x, B1.y, B1.z, B1.w};
    h16x8 outv;
#pragma unroll
    for (int k = 0; k < 8; k++) {
        float o = fmaf(acc[k], inv * Av[k], Bv[k]);
        o = o > 0.f ? o : expm1f(o);
        outv[k] = (_Float16)o;
    }
    *(h16x8*)&oh[((size_t)v << 7) + ch] = outv;
}

// ---------------- final aggregate (4-lane group = node), fp32, HC=16 --------

__global__ __launch_bounds__(256) void agg_f(
    const float* __restrict__ xl, const float* __restrict__ xr,
    const int* __restrict__ rowptr, const int* __restrict__ col,
    const float* __restrict__ att, const float* __restrict__ bias,
    float* __restrict__ out, int n) {
    int v = (blockIdx.x * blockDim.x + threadIdx.x) >> 2;
    if (v >= n) return;
    int L = threadIdx.x & 3;
    int ch = 4 * L;

    int beg = rowptr[v];
    int end = rowptr[v + 1];
    int cb = beg;
    int cidx = (cb + L < end) ? col[cb + L] : v;   // 4-edge window

    float4 xrv = *(const float4*)&xr[((size_t)v << 4) + ch];
    float4 av = *(const float4*)&att[ch];

    float lrun = 0.f;
    float4 acc = make_float4(0.f, 0.f, 0.f, 0.f);

    while (true) {
        float4 xv[4];
#pragma unroll
        for (int j = 0; j < 4; j++) {
            int u = __shfl(cidx, j, 4);            // masked slots -> v
            xv[j] = *(const float4*)&xl[((size_t)u << 4) + ch];
        }
#pragma unroll
        for (int j = 0; j < 4; j++) {
            bool ok = (cb + j < end);
            float s0 = xv[j].x + xrv.x; s0 = s0 > 0.f ? s0 : NEG * s0;
            float s1 = xv[j].y + xrv.y; s1 = s1 > 0.f ? s1 : NEG * s1;
            float s2 = xv[j].z + xrv.z; s2 = s2 > 0.f ? s2 : NEG * s2;
            float s3 = xv[j].w + xrv.w; s3 = s3 > 0.f ? s3 : NEG * s3;
            float part = fmaf(s0, av.x, fmaf(s1, av.y, fmaf(s2, av.z, s3 * av.w)));
            part += __shfl_xor(part, 1);
            part += __shfl_xor(part, 2);
            float p = ok ? __expf(part) : 0.f;
            lrun += p;
            acc.x = fmaf(p, xv[j].x, acc.x);
            acc.y = fmaf(p, xv[j].y, acc.y);
            acc.z = fmaf(p, xv[j].z, acc.z);
            acc.w = fmaf(p, xv[j].w, acc.w);
        }
        cb += 4;
        if (cb >= end) break;
        cidx = (cb + L < end) ? col[cb + L] : v;
    }

    float inv = 1.0f / lrun;
    float4 b4 = *(const float4*)&bias[ch];
    *(float4*)&out[((size_t)v << 4) + ch] =
        make_float4(fmaf(acc.x, inv, b4.x), fmaf(acc.y, inv, b4.y),
                    fmaf(acc.z, inv, b4.z), fmaf(acc.w, inv, b4.w));
}

// ---------------- launch ----------------

extern "C" void kernel_launch(void* const* d_in, const int* in_sizes, int n_in,
                              void* d_out, int out_size, void* d_ws, size_t ws_size,
                              hipStream_t stream) {
    const float* x = (const float*)d_in[0];
    const int* ei = (const int*)d_in[1];
    const float* Wl[4] = {(const float*)d_in[2], (const float*)d_in[6],
                          (const float*)d_in[10], (const float*)d_in[14]};
    const float* Wr[4] = {(const float*)d_in[3], (const float*)d_in[7],
                          (const float*)d_in[11], (const float*)d_in[15]};
    const float* att[4] = {(const float*)d_in[4], (const float*)d_in[8],
                           (const float*)d_in[12], (const float*)d_in[16]};
    const float* bias[4] = {(const float*)d_in[5], (const float*)d_in[9],
                            (const float*)d_in[13], (const float*)d_in[17]};
    const float* g[3] = {(const float*)d_in[18], (const float*)d_in[22], (const float*)d_in[26]};
    const float* be[3] = {(const float*)d_in[19], (const float*)d_in[23], (const float*)d_in[27]};
    const float* bm[3] = {(const float*)d_in[20], (const float*)d_in[24], (const float*)d_in[28]};
    const float* bv[3] = {(const float*)d_in[21], (const float*)d_in[25], (const float*)d_in[29]};

    const int n = in_sizes[0] / 128;
    const int E = in_sizes[1] / 2;
    const int ET = E + n;

    char* p = (char*)d_ws;
    __half* xh = (__half*)p;           p += (size_t)n * 128 * 2;
    __half* xlh = (__half*)p;          p += (size_t)n * 128 * 2;
    __half* xrh = (__half*)p;          p += (size_t)n * 128 * 2;
    float* xl3 = (float*)p;            p += (size_t)n * 16 * 4;
    float* xr3 = (float*)p;            p += (size_t)n * 16 * 4;
    int* rowraw = (int*)p;            p += (size_t)(n + 4) * 4;
    int* rowfin = (int*)p;            p += (size_t)(n + 4) * 4;
    int* cnt = (int*)p;               p += (size_t)n * 4;
    int* fill = (int*)p;              p += (size_t)n * 4;   // contiguous after cnt
    int* col = (int*)p;               p += (size_t)ET * 4;
    int* bsums = (int*)p;             p += 256;
    __half* pk[4];
    for (int i = 0; i < 3; i++) { pk[i] = (__half*)p; p += 4 * 16 * 512 * 2; }
    pk[3] = (__half*)p;               p += 4 * 2 * 512 * 2;
    float* bnA = (float*)p;           p += 384 * 4;
    float* bnB = (float*)p;           p += 384 * 4;

    // one memset over cnt+fill (adjacent, 8n bytes)
    (void)hipMemsetAsync(cnt, 0, (size_t)n * 8, stream);

    const int tb = 256;
    const int histBlocks = (ET + tb - 1) / tb;
    hist_pack<<<201 + histBlocks, tb, 0, stream>>>(
        ei, E, n, cnt,
        Wl[0], Wr[0], Wl[1], Wr[1], Wl[2], Wr[2], Wl[3], Wr[3],
        pk[0], pk[1], pk[2], pk[3],
        bias[0], bias[1], bias[2],
        g[0], g[1], g[2], be[0], be[1], be[2],
        bm[0], bm[1], bm[2], bv[0], bv[1], bv[2],
        bnA, bnB);

    const int nb = (n + 1023) / 1024;
    const int gb64 = (n + 63) / 64;
    const int gemmBlocksSmall = ((n + 15) / 16 + 3) / 4;
    const int aggBlocksH = (n + 15) / 16;   // 16-lane group per node
    const int aggBlocksF = (n + 63) / 64;   // 4-lane group per node

    // scan_block co-dispatched with layer-0 GEMM (independent work)
    scanblk_gemm0<<<nb + gb64, 256, 0, stream>>>(
        cnt, rowraw, bsums, n, nb, x, pk[0], xlh, xrh);
    // finalize rowfin + scatter col in ONE dispatch (no GEMM co-residency)
    scatfin<<<nb + histBlocks, tb, 0, stream>>>(
        ei, E, n, rowraw, bsums, nb, fill, col, rowfin, nb);

    agg_h<<<aggBlocksH, 256, 0, stream>>>(
        xlh, xrh, rowfin, col, att[0], bnA, bnB, xh, n);
    for (int i = 1; i < 3; i++) {
        gemm_h_big2<<<gb64, 256, 0, stream>>>(xh, pk[i], xlh, xrh, n);
        agg_h<<<aggBlocksH, 256, 0, stream>>>(
            xlh, xrh, rowfin, col, att[i], bnA + 128 * i, bnB + 128 * i, xh, n);
    }
    gemm_h_small<<<gemmBlocksSmall, 256, 0, stream>>>(xh, pk[3], xl3, xr3, n);
    agg_f<<<aggBlocksF, 256, 0, stream>>>(
        xl3, xr3, rowfin, col, att[3], bias[3], (float*)d_out, n);
}